// Round 14
// baseline (2313.013 us; speedup 1.0000x reference)
//
#include <hip/hip_runtime.h>
#include <hip/hip_bf16.h>
#include <cstdint>

// B=256, T=512, D_IN=256, D_H=512, D_P=512. Inputs/outputs are FLOAT32.
// Internals run in bf16 MFMA with f32 accumulate.
#define RB   256
#define RT   512
#define ROWS (RB*RT)   // 131072

typedef __attribute__((ext_vector_type(8))) short bf16x8;
typedef __attribute__((ext_vector_type(4))) short s16x4;
typedef __attribute__((ext_vector_type(4))) float f32x4;
typedef __attribute__((ext_vector_type(4))) int   i32x4;
typedef unsigned long long ull;

#define DEV static __device__ __forceinline__

DEV float bf2f(unsigned short u){
  union { unsigned int i; float f; } v; v.i = ((unsigned int)u) << 16; return v.f;
}
DEV float blo(unsigned int u){
  union { unsigned int i; float f; } v; v.i = u << 16; return v.f;
}
DEV float bhi(unsigned int u){
  union { unsigned int i; float f; } v; v.i = u & 0xffff0000u; return v.f;
}
DEV unsigned short f2bf(float f){
  union { float f; unsigned int i; } v; v.f = f;
  unsigned int x = v.i;
  return (unsigned short)((x + 0x7fffu + ((x >> 16) & 1u)) >> 16);   // RNE
}
DEV unsigned int cvt_pk_bf16(float lo, float hi){   // RNE, bit-identical to f2bf
  unsigned int r;
  asm("v_cvt_pk_bf16_f32 %0, %1, %2" : "=v"(r) : "v"(lo), "v"(hi));
  return r;
}
DEV float tanh_fast(float x){
  // No clamp needed: e=inf -> rcp=0 -> 1.0; e=0 -> rcp(1)=1 -> -1.0 (exact saturation).
  float e  = __expf(2.f * x);
  return 1.f - 2.f * __builtin_amdgcn_rcpf(e + 1.f);
}
DEV float sigmoid_fast(float x){
  float xc = fminf(fmaxf(x, -30.f), 30.f);
  return __builtin_amdgcn_rcpf(1.f + __expf(-xc));
}
DEV void gl_lds16(const void* g, void* l){
  __builtin_amdgcn_global_load_lds(
      (const __attribute__((address_space(1))) unsigned int*)g,
      (__attribute__((address_space(3))) unsigned int*)l, 16, 0, 0);
}

// ---------------------------------------------------------------------------
// f32 -> bf16 conversion of all 15 input tensors (one launch, 4 elems/thread).
// ---------------------------------------------------------------------------
struct ConvArgs {
  const float* src[15];
  unsigned short* dst[15];
  long pre[16];          // prefix sums in 4-element chunks
};

__global__ __launch_bounds__(256) void conv_k(ConvArgs a, long total)
{
  long stride = (long)gridDim.x * blockDim.x;
  for (long idx = (long)blockIdx.x * blockDim.x + threadIdx.x; idx < total; idx += stride){
    int t = 0;
    #pragma unroll
    for (int j = 0; j < 14; j++) t += (idx >= a.pre[j + 1]) ? 1 : 0;
    long local = idx - a.pre[t];
    float4 v = ((const float4*)a.src[t])[local];
    s16x4 o;
    o[0] = (short)f2bf(v.x); o[1] = (short)f2bf(v.y);
    o[2] = (short)f2bf(v.z); o[3] = (short)f2bf(v.w);
    ((s16x4*)a.dst[t])[local] = o;
  }
}

// ---------------------------------------------------------------------------
// W_hh tail repack (ks 12..15) into fragment order so recur's streamed
// per-step frag loads are perfectly lane-coalesced L2 reads (v4-verified
// pattern). Frag fi = w*16 + (ks-12)*4 + nt; Wt[(fi*64+l)*8..+8] holds
// Whh[(w*64 + nt*16 + (l&15))*512 + ks*32 + (l>>4)*8 ..+8].
// ---------------------------------------------------------------------------
__global__ __launch_bounds__(256) void wtail_k(
    const unsigned short* __restrict__ Whh, unsigned short* __restrict__ Wt)
{
  int id = blockIdx.x * 256 + threadIdx.x;   // 0..8191
  int fi = id >> 6, l = id & 63;
  int w  = fi >> 4, si = (fi >> 2) & 3, nt = fi & 3;
  int row = w*64 + nt*16 + (l & 15);
  int col = (12 + si)*32 + (l >> 4)*8;
  *(bf16x8*)&Wt[(long)id * 8] = *(const bf16x8*)&Whh[row*512 + col];
}

// ---------------------------------------------------------------------------
// Generic C[r,c] = act(A @ W^T + bias (+bias2) (+addsrc)),  C is ROWSx512.
// 128x128 tile, BK=64, 4 waves (2x2 of 64x64), mfma_f32_16x16x32_bf16.
// Double-buffered LDS K-pipeline: stage(next) before compute(cur); counted
// s_waitcnt vmcnt(8); raw s_barrier. 64 KB LDS -> 2 blk/CU.
// ---------------------------------------------------------------------------
__global__ __launch_bounds__(256, 2) void gemm_k(
    const unsigned short* __restrict__ A, int lda,
    const unsigned short* __restrict__ W, int ldb,
    const unsigned short* __restrict__ bias,
    const unsigned short* __restrict__ bias2,
    const unsigned short* __restrict__ addsrc,
    void* __restrict__ C,
    int K, int act, int out_f32)
{
  __shared__ unsigned short As[2][128*64];
  __shared__ unsigned short Bs[2][128*64];
  const int tid = threadIdx.x, w = tid >> 6, l = tid & 63;
  const int wm = w >> 1, wn = w & 1;
  const int lr = l & 15, lk = (l >> 4) * 8;
  const long row0 = (long)blockIdx.x * 128;
  const int  col0 = blockIdx.y * 128;

  f32x4 acc[4][4] = {};

#define GSTAGE(buf, kk) { \
    _Pragma("unroll") \
    for (int i = 0; i < 4; i++){ \
      int chunk = i*256 + tid; \
      int r = chunk >> 3, kc = (chunk & 7) * 8; \
      gl_lds16(A + (row0 + r)*lda + (kk) + kc, (unsigned short*)As[buf] + (i*256 + w*64)*8); \
      gl_lds16(W + (long)(col0 + r)*ldb + (kk) + kc, (unsigned short*)Bs[buf] + (i*256 + w*64)*8); \
    } }

  GSTAGE(0, 0)
  const int nst = K >> 6;
  for (int s = 0; s < nst; s++){
    const int cb = s & 1;
    if (s + 1 < nst){
      GSTAGE(cb ^ 1, (s + 1) * 64)
      asm volatile("s_waitcnt vmcnt(8)" ::: "memory");   // cur's 8 done; next's fly
    } else {
      asm volatile("s_waitcnt vmcnt(0)" ::: "memory");
    }
    __builtin_amdgcn_s_barrier();
    asm volatile("" ::: "memory");
    #pragma unroll
    for (int ks = 0; ks < 2; ks++){
      bf16x8 a[4], b[4];
      #pragma unroll
      for (int mt = 0; mt < 4; mt++) a[mt] = *(const bf16x8*)&As[cb][(wm*64 + mt*16 + lr)*64 + ks*32 + lk];
      #pragma unroll
      for (int nt = 0; nt < 4; nt++) b[nt] = *(const bf16x8*)&Bs[cb][(wn*64 + nt*16 + lr)*64 + ks*32 + lk];
      #pragma unroll
      for (int mt = 0; mt < 4; mt++)
        #pragma unroll
        for (int nt = 0; nt < 4; nt++)
          acc[mt][nt] = __builtin_amdgcn_mfma_f32_16x16x32_bf16(a[mt], b[nt], acc[mt][nt], 0, 0, 0);
    }
    asm volatile("s_waitcnt lgkmcnt(0)" ::: "memory");   // LDS reads done
    __builtin_amdgcn_s_barrier();
    asm volatile("" ::: "memory");
  }
#undef GSTAGE

  #pragma unroll
  for (int nt = 0; nt < 4; nt++){
    int c = col0 + wn*64 + nt*16 + lr;
    float bv = bf2f(bias[c]);
    if (bias2) bv += bf2f(bias2[c]);
    #pragma unroll
    for (int mt = 0; mt < 4; mt++){
      #pragma unroll
      for (int i = 0; i < 4; i++){
        long r = row0 + wm*64 + mt*16 + (l >> 4)*4 + i;
        float v = acc[mt][nt][i] + bv;
        if (addsrc) v += bf2f(addsrc[r*512 + c]);
        if (act) v = fmaxf(v, 0.f);
        if (out_f32) ((float*)C)[r*512 + c] = v;
        else ((unsigned short*)C)[r*512 + c] = f2bf(v);
      }
    }
  }
}

// ---------------------------------------------------------------------------
// Recurrence v16: h_t = tanh(x_ih[:,t,:] + h_{t-1} @ W_hh^T), H[:,t,:] = h_t.
//
// NO CROSS-BLOCK EXCHANGE. 8 rounds of MALL-protocol tuning (v6..v15) all
// landed at 1160-1270us: cross-XCD store->remote-visibility is ~3000+cyc on
// this part regardless of scope, and the spin showed as 200 GB FETCH. v16
// keeps each batch group's ENTIRE K=512 within one block:
//   16 blocks (one per 16-row batch group) x 512 threads = 8 waves (2/SIMD,
//   256-reg budget). Wave owns 64 cols. Its 64 weight frags split 3 ways:
//     - ks 0..7  : 32 frags PINNED in regs (128 regs; v8-proven pin)
//     - ks 8..11 : 16 frags from LDS (128 KB staged once, frag-ordered)
//     - ks 12..15: 16 frags streamed per-step from frag-ordered Wt in L2
//                  (two batches of 8 -> only 32 landing regs; 2-wave TLP
//                  hides the L2 latency)
//   h exchanged through LDS only (frag-ordered 16 KB tile, 2 barriers/step,
//   v5-proven pattern). Per-CU step: LDS ~3100cyc || L2 2050 || MFMA 640.
// Zero deadlock surface. MFMA ks ascending 0..15 per acc[nt] with identical
// fragment values => bit-identical numerics.
// ---------------------------------------------------------------------------
__global__ __launch_bounds__(512, 2) void recur_k(
    const unsigned short* __restrict__ xih,   // (B,T,512) bf16
    const unsigned short* __restrict__ Whh,   // (512,512) bf16
    const unsigned short* __restrict__ Wt,    // frag-ordered ks12..15 (128 KB)
    unsigned short* __restrict__ H)           // (B,T,512) bf16
{
  extern __shared__ unsigned short lds[];     // 147,456 B
  unsigned short* Wl = lds;                   // 128 frags x 512 shorts (ks8..11)
  unsigned short* hx = lds + 65536;           // 16 frags x 512 shorts (h tile)

  const int tid = threadIdx.x, w = tid >> 6, l = tid & 63;
  const int lr = l & 15, hi = l >> 4;
  const int b0 = blockIdx.x * 16;
  const int cbase = w * 64;

  // Stage ks8..11 weight frags into LDS (frag fl = w*16 + si*4 + nt).
  #pragma unroll
  for (int i = 0; i < 16; i++){
    int cid = i*512 + tid;                    // 8192 16B chunks
    int fl = cid >> 6, ln = cid & 63;
    int fw = fl >> 4, si = (fl >> 2) & 3, fnt = fl & 3;
    int row = fw*64 + fnt*16 + (ln & 15);
    int col = (8 + si)*32 + (ln >> 4)*8;
    *(bf16x8*)&Wl[fl*512 + ln*8] = *(const bf16x8*)&Whh[row*512 + col];
  }
  // Zero h tile (h_0 = 0).
  {
    ull* z = (ull*)hx;
    for (int i = tid; i < 2048; i += 512) z[i] = 0;
  }

  // Pin ks0..7 frags in registers (un-rematerializable; backed by the
  // unified VGPR/AGPR file -- v8-proven).
  bf16x8 wa[4][8];
  #pragma unroll
  for (int nt = 0; nt < 4; nt++){
    const unsigned short* wp = Whh + (cbase + nt*16 + lr)*512 + hi*8;
    #pragma unroll
    for (int ks = 0; ks < 8; ks++)
      wa[nt][ks] = *(const bf16x8*)&wp[ks*32];
  }
  #pragma unroll
  for (int nt = 0; nt < 4; nt++)
    #pragma unroll
    for (int ks = 0; ks < 8; ks++)
      asm volatile("" : "+v"(wa[nt][ks]));

  __syncthreads();

  const unsigned short* hrd = hx + l*8;                  // + ks*512
  const unsigned short* wlb = Wl + (w*16)*512 + l*8;     // + (si*4+nt)*512
  const unsigned short* wtb = Wt + ((long)w*16*64 + l)*8;// + j*512 (shorts)

  const long xb = ((long)(b0 + lr) * RT) * 512 + cbase + hi*4;
  const unsigned short* xr = xih + xb;        // +nt*16; advances 512/step
  unsigned short*       hr = H   + xb;

  // h-frag write slots: value (col c = cbase+nt*16+hi*4+i, batch lr) lives in
  // frag c>>5 = 2w+(nt>>1), short off (((nt&1)*2+(hi>>1))*16+lr)*8+(hi&1)*4.
  unsigned short* hw0 = hx + (2*w    )*512;   // frags for nt 0,1
  unsigned short* hw1 = hx + (2*w + 1)*512;   // frags for nt 2,3
  const int so0 = (((hi >> 1)    )*16 + lr)*8 + (hi & 1)*4;   // nt even
  const int so1 = ((2 + (hi >> 1))*16 + lr)*8 + (hi & 1)*4;   // nt odd

  uint2 xu[4];
  #pragma unroll
  for (int nt = 0; nt < 4; nt++) xu[nt] = *(const uint2*)(xr + nt*16);

  #pragma unroll 1
  for (int t = 0; t < RT; t++){
    // Batch-1 stream loads (ks12,13 = frags j 0..7); fly under reg-MFMAs.
    bf16x8 s1[8];
    #pragma unroll
    for (int j = 0; j < 8; j++) s1[j] = *(const bf16x8*)(wtb + j*512);

    f32x4 acc[4] = {};
    // ks 0..7 from pinned registers.
    #pragma unroll
    for (int ks = 0; ks < 8; ks++){
      bf16x8 hf = *(const bf16x8*)(hrd + ks*512);
      #pragma unroll
      for (int nt = 0; nt < 4; nt++)
        acc[nt] = __builtin_amdgcn_mfma_f32_16x16x32_bf16(wa[nt][ks], hf, acc[nt], 0, 0, 0);
    }
    // ks 8..11 from LDS.
    #pragma unroll
    for (int si = 0; si < 4; si++){
      bf16x8 hf = *(const bf16x8*)(hrd + (8 + si)*512);
      #pragma unroll
      for (int nt = 0; nt < 4; nt++){
        bf16x8 af = *(const bf16x8*)(wlb + (si*4 + nt)*512);
        acc[nt] = __builtin_amdgcn_mfma_f32_16x16x32_bf16(af, hf, acc[nt], 0, 0, 0);
      }
    }
    // ks 12..13 from batch-1 (compiler inserts the vmcnt wait).
    #pragma unroll
    for (int si = 0; si < 2; si++){
      bf16x8 hf = *(const bf16x8*)(hrd + (12 + si)*512);
      #pragma unroll
      for (int nt = 0; nt < 4; nt++)
        acc[nt] = __builtin_amdgcn_mfma_f32_16x16x32_bf16(s1[si*4 + nt], hf, acc[nt], 0, 0, 0);
    }
    // Batch-2 stream loads (ks14,15 = frags j 8..15); latency hidden by the
    // co-resident wave on this SIMD (2 waves/SIMD).
    bf16x8 s2[8];
    #pragma unroll
    for (int j = 0; j < 8; j++) s2[j] = *(const bf16x8*)(wtb + (8 + j)*512);
    #pragma unroll
    for (int si = 0; si < 2; si++){
      bf16x8 hf = *(const bf16x8*)(hrd + (14 + si)*512);
      #pragma unroll
      for (int nt = 0; nt < 4; nt++)
        acc[nt] = __builtin_amdgcn_mfma_f32_16x16x32_bf16(s2[si*4 + nt], hf, acc[nt], 0, 0, 0);
    }

    // h = tanh(acc + x_ih), pack (RNE, bit-identical).
    uint2 P[4];
    #pragma unroll
    for (int nt = 0; nt < 4; nt++){
      float v0 = tanh_fast(acc[nt][0] + blo(xu[nt].x));
      float v1 = tanh_fast(acc[nt][1] + bhi(xu[nt].x));
      float v2 = tanh_fast(acc[nt][2] + blo(xu[nt].y));
      float v3 = tanh_fast(acc[nt][3] + bhi(xu[nt].y));
      P[nt].x = cvt_pk_bf16(v0, v1);
      P[nt].y = cvt_pk_bf16(v2, v3);
    }

    // Prefetch next x_ih.
    if (t + 1 < RT){
      #pragma unroll
      for (int nt = 0; nt < 4; nt++) xu[nt] = *(const uint2*)(xr + 512 + nt*16);
    }
    xr += 512;

    // Barrier A: all reads of h_{t-1} done (LDS-only wait; no store drain).
    asm volatile("s_waitcnt lgkmcnt(0)" ::: "memory");
    __builtin_amdgcn_s_barrier();
    asm volatile("" ::: "memory");

    // Write h_t: LDS frags (for next step) + global H (coalesced b64s).
    *(uint2*)(hw0 + so0) = P[0];
    *(uint2*)(hw0 + so1) = P[1];
    *(uint2*)(hw1 + so0) = P[2];
    *(uint2*)(hw1 + so1) = P[3];
    #pragma unroll
    for (int nt = 0; nt < 4; nt++)
      *(uint2*)(hr + nt*16) = P[nt];
    hr += 512;

    // Barrier B: h_t visible to all waves.
    asm volatile("s_waitcnt lgkmcnt(0)" ::: "memory");
    __builtin_amdgcn_s_barrier();
    asm volatile("" ::: "memory");
  }
}

// ---------------------------------------------------------------------------
// Fused blend: gate = sigmoid([x|h]@W_g^T + b_g); x_proj = x@W_ip^T + b_ip;
// h_proj = h@W_hp^T + b_hp; out = gate*h_proj + (1-gate)*x_proj.
// Two-phase K=768 (phase1: x/K=256 with acc_p=x_proj snapshot; phase2: h/K=512).
// ---------------------------------------------------------------------------
__global__ __launch_bounds__(256, 2) void blend_k(
    const unsigned short* __restrict__ X,    // (ROWS,256) bf16
    const unsigned short* __restrict__ Hm,   // (ROWS,512) bf16
    const unsigned short* __restrict__ Wg,   // (512,768) bf16
    const unsigned short* __restrict__ Wip,  // (512,256) bf16
    const unsigned short* __restrict__ Whp,  // (512,512) bf16
    const unsigned short* __restrict__ bg,
    const unsigned short* __restrict__ bip,
    const unsigned short* __restrict__ bhp,
    unsigned short* __restrict__ Out)
{
  __shared__ unsigned short As[128*64];
  __shared__ unsigned short Gs[128*64];
  __shared__ unsigned short Ps[128*64];
  const int tid = threadIdx.x, w = tid >> 6, l = tid & 63;
  const int wm = w >> 1, wn = w & 1;
  const int lr = l & 15, lk = (l >> 4) * 8;
  const long row0 = (long)blockIdx.x * 128;
  const int  col0 = blockIdx.y * 128;

  f32x4 accg[4][4] = {}, accp[4][4] = {};
  unsigned int xpp[4][4][2];

  #pragma unroll 1
  for (int k0 = 0; k0 < 768; k0 += 64){
    const bool ph1 = (k0 < 256);
    __syncthreads();
    #pragma unroll
    for (int i = 0; i < 4; i++){
      int chunk = i*256 + tid;
      int r = chunk >> 3, kc = (chunk & 7) * 8;
      const unsigned short* asrc = ph1 ? (X  + (row0 + r)*256 + k0 + kc)
                                       : (Hm + (row0 + r)*512 + (k0 - 256) + kc);
      gl_lds16(asrc, (unsigned short*)As + (i*256 + w*64)*8);
      gl_lds16(Wg + (long)(col0 + r)*768 + k0 + kc, (unsigned short*)Gs + (i*256 + w*64)*8);
      const unsigned short* psrc = ph1 ? (Wip + (col0 + r)*256 + k0 + kc)
                                       : (Whp + (col0 + r)*512 + (k0 - 256) + kc);
      gl_lds16(psrc, (unsigned short*)Ps + (i*256 + w*64)*8);
    }
    asm volatile("s_waitcnt vmcnt(0)" ::: "memory");
    __syncthreads();
    #pragma unroll
    for (int ks = 0; ks < 2; ks++){
      bf16x8 a[4], gq[4], pq[4];
      #pragma unroll
      for (int mt = 0; mt < 4; mt++) a[mt]  = *(const bf16x8*)&As[(wm*64 + mt*16 + lr)*64 + ks*32 + lk];
      #pragma unroll
      for (int nt = 0; nt < 4; nt++){
        gq[nt] = *(const bf16x8*)&Gs[(wn*64 + nt*16 + lr)*64 + ks*32 + lk];
        pq[nt] = *(const bf16x8*)&Ps[(wn*64 + nt*16 + lr)*64 + ks*32 + lk];
      }
      #pragma unroll
      for (int mt = 0; mt < 4; mt++)
        #pragma unroll
        for (int nt = 0; nt < 4; nt++){
          accg[mt][nt] = __builtin_amdgcn_mfma_f32_16x16x32_bf16(a[mt], gq[nt], accg[mt][nt], 0, 0, 0);
          accp[mt][nt] = __builtin_amdgcn_mfma_f32_16x16x32_bf16(a[mt], pq[nt], accp[mt][nt], 0, 0, 0);
        }
    }
    if (k0 == 192){   // end of phase 1: snapshot x_proj, reset acc_p for h_proj
      #pragma unroll
      for (int mt = 0; mt < 4; mt++)
        #pragma unroll
        for (int nt = 0; nt < 4; nt++){
          xpp[mt][nt][0] = (unsigned)f2bf(accp[mt][nt][0]) | ((unsigned)f2bf(accp[mt][nt][1]) << 16);
          xpp[mt][nt][1] = (unsigned)f2bf(accp[mt][nt][2]) | ((unsigned)f2bf(accp[mt][nt][3]) << 16);
          accp[mt][nt] = (f32x4){0.f, 0.f, 0.f, 0.f};
        }
    }
  }

  #pragma unroll
  for (int nt = 0; nt < 4; nt++){
    int c = col0 + wn*64 + nt*16 + lr;
    float bgv = bf2f(bg[c]), bipv = bf2f(bip[c]), bhpv = bf2f(bhp[c]);
    #pragma unroll
    for (int mt = 0; mt < 4; mt++){
      #pragma unroll
      for (int i = 0; i < 4; i++){
        long r = row0 + wm*64 + mt*16 + (l >> 4)*4 + i;
        float g  = sigmoid_fast(accg[mt][nt][i] + bgv);
        float hp = accp[mt][nt][i] + bhpv;
        unsigned u = xpp[mt][nt][i >> 1];
        float xp = bf2f((unsigned short)((i & 1) ? (u >> 16) : (u & 0xffff))) + bipv;
        float v = g * hp + (1.f - g) * xp;
        Out[r*512 + c] = f2bf(v);
      }
    }
  }
}

// ---------------------------------------------------------------------------
// Buffer plan. d_out (268 MB, f32 final) doubles as bf16 scratch; W_o/b_o
// live in d_ws so K5 never reads what it writes:
//   d_out [0, 64Mi):             x_bf16 (67.1 MB)
//   d_out [64Mi, +2.9MB):        converted weights W_ih..b_r
//   d_out [72Mi, +134MB):        x_ih, later blended (bf16)  [ends 209,715,200)
//   d_out [209,715,200, +128KB): Wt (frag-ordered W_hh ks12..15)
//   d_ws  [0, 134MB):            H, later u (bf16)
//   d_ws  [134MB, +525KB):       W_o, b_o (bf16)
// conv -> wtail -> K1(x_ih) -> K2(H) -> K3(blended) -> K4(u) -> K5(f32 out).
// Every stage's read set is disjoint from its write set.
// ---------------------------------------------------------------------------
extern "C" void kernel_launch(void* const* d_in, const int* in_sizes, int n_in,
                              void* d_out, int out_size, void* d_ws, size_t ws_size,
                              hipStream_t stream)
{
  static const long nelem[15] = {
    (long)ROWS*256,        // x
    512*256, 512,          // W_ih, b_ih
    512*512, 512,          // W_hh, b_hh
    512*256, 512,          // W_ip, b_ip
    512*512, 512,          // W_hp, b_hp
    512*768, 512,          // W_g,  b_g
    512*512, 512,          // W_r,  b_r
    512*512, 512           // W_o,  b_o
  };

  unsigned char* ob = (unsigned char*)d_out;
  unsigned char* wb = (unsigned char*)d_ws;
  ConvArgs ca;
  long pre = 0;
  size_t doff = 0;
  for (int i = 0; i < 15; i++){
    ca.src[i] = (const float*)d_in[i];
    if (i == 13)      ca.dst[i] = (unsigned short*)(wb + 134217728u);   // W_o
    else if (i == 14) ca.dst[i] = (unsigned short*)(wb + 134742016u);   // b_o
    else              ca.dst[i] = (unsigned short*)(ob + doff);
    ca.pre[i] = pre;
    pre += nelem[i] / 4;
    if (i == 0) doff = 67108864u;
    else if (i < 13) doff += (size_t)nelem[i] * 2;
  }
  ca.pre[15] = pre;
  const long total_chunks = pre;   // 8,815,488

  const unsigned short* xb  = ca.dst[0];
  const unsigned short* Wih = ca.dst[1];
  const unsigned short* bih = ca.dst[2];
  const unsigned short* Whh = ca.dst[3];
  const unsigned short* bhh = ca.dst[4];
  const unsigned short* Wip = ca.dst[5];
  const unsigned short* bip = ca.dst[6];
  const unsigned short* Whp = ca.dst[7];
  const unsigned short* bhp = ca.dst[8];
  const unsigned short* Wg  = ca.dst[9];
  const unsigned short* bg  = ca.dst[10];
  const unsigned short* Wr  = ca.dst[11];
  const unsigned short* br  = ca.dst[12];
  const unsigned short* Wo  = ca.dst[13];
  const unsigned short* bo  = ca.dst[14];

  unsigned short* xih  = (unsigned short*)(ob + 75497472u);    // 72 MiB offset
  unsigned short* Wtl  = (unsigned short*)(ob + 209715200u);   // 128 KB repack
  unsigned short* wsb  = (unsigned short*)d_ws;                // H, later u

  dim3 grid(ROWS / 128, 4), block(256);

  // K0: convert all f32 inputs to bf16.
  conv_k<<<2048, 256, 0, stream>>>(ca, total_chunks);

  // K0b: repack W_hh ks12..15 into fragment order for recur streaming.
  wtail_k<<<32, 256, 0, stream>>>(Whh, Wtl);

  // K1: x_ih = x @ W_ih^T + b_ih + b_hh  -> xih (bf16)
  gemm_k<<<grid, block, 0, stream>>>(xb, 256, Wih, 256, bih, bhh, nullptr, xih, 256, 0, 0);

  // K2: recurrence -> H in ws (16 blocks x 512 threads, 147,456 B dyn LDS)
  static const int kRecurLds = 128*1024 + 16*1024;   // 147,456
  (void)hipFuncSetAttribute((const void*)recur_k, hipFuncAttributeMaxDynamicSharedMemorySize, kRecurLds);
  recur_k<<<16, 512, kRecurLds, stream>>>(xih, Whh, Wtl, wsb);

  // K3: blended (fused gate/x_proj/h_proj) -> xih region (x_ih dead)
  blend_k<<<grid, block, 0, stream>>>(xb, wsb, Wg, Wip, Whp, bg, bip, bhp, xih);

  // K4: u = relu(blended @ W_r^T + b_r + blended) -> ws (H dead)
  gemm_k<<<grid, block, 0, stream>>>(xih, 512, Wr, 512, br, nullptr, xih, wsb, 512, 1, 0);

  // K5: out = u @ W_o^T + b_o -> d_out (f32; reads only from d_ws)
  gemm_k<<<grid, block, 0, stream>>>(wsb, 512, Wo, 512, bo, nullptr, nullptr, d_out, 512, 0, 1);
}

// Round 15
// 1929.850 us; speedup vs baseline: 1.1985x; 1.1985x over previous
//
#include <hip/hip_runtime.h>
#include <hip/hip_bf16.h>
#include <cstdint>

// B=256, T=512, D_IN=256, D_H=512, D_P=512. Inputs/outputs are FLOAT32.
// Internals run in bf16 MFMA with f32 accumulate.
#define RB   256
#define RT   512
#define ROWS (RB*RT)   // 131072

typedef __attribute__((ext_vector_type(8))) short bf16x8;
typedef __attribute__((ext_vector_type(4))) short s16x4;
typedef __attribute__((ext_vector_type(4))) float f32x4;
typedef __attribute__((ext_vector_type(4))) int   i32x4;
typedef unsigned long long ull;

#define DEV static __device__ __forceinline__

DEV float bf2f(unsigned short u){
  union { unsigned int i; float f; } v; v.i = ((unsigned int)u) << 16; return v.f;
}
DEV float blo(unsigned int u){
  union { unsigned int i; float f; } v; v.i = u << 16; return v.f;
}
DEV float bhi(unsigned int u){
  union { unsigned int i; float f; } v; v.i = u & 0xffff0000u; return v.f;
}
DEV unsigned short f2bf(float f){
  union { float f; unsigned int i; } v; v.f = f;
  unsigned int x = v.i;
  return (unsigned short)((x + 0x7fffu + ((x >> 16) & 1u)) >> 16);   // RNE
}
DEV unsigned int cvt_pk_bf16(float lo, float hi){   // RNE, bit-identical to f2bf
  unsigned int r;
  asm("v_cvt_pk_bf16_f32 %0, %1, %2" : "=v"(r) : "v"(lo), "v"(hi));
  return r;
}
DEV float tanh_fast(float x){
  // No clamp needed: e=inf -> rcp=0 -> 1.0; e=0 -> rcp(1)=1 -> -1.0 (exact saturation).
  float e  = __expf(2.f * x);
  return 1.f - 2.f * __builtin_amdgcn_rcpf(e + 1.f);
}
DEV float sigmoid_fast(float x){
  float xc = fminf(fmaxf(x, -30.f), 30.f);
  return __builtin_amdgcn_rcpf(1.f + __expf(-xc));
}
DEV void gl_lds16(const void* g, void* l){
  __builtin_amdgcn_global_load_lds(
      (const __attribute__((address_space(1))) unsigned int*)g,
      (__attribute__((address_space(3))) unsigned int*)l, 16, 0, 0);
}
// 16B system-scope (MALL-coherent) store/load — the v10-proven exchange ops.
// Non-atomic at 16B, but aligned dwords land atomically, and every dword is
// self-tagged. (Round-12 lesson: scope bits are the (sc1,sc0) PAIR; sc0-only
// is SE scope and deadlocks. sc0 sc1 = system scope, proven correct 4x.)
DEV void st16_mall(void* p, i32x4 v){
  asm volatile("global_store_dwordx4 %0, %1, off sc0 sc1"
               :: "v"(p), "v"(v) : "memory");
}
DEV i32x4 ld16_mall(const void* p){
  i32x4 r;
  asm volatile("global_load_dwordx4 %0, %1, off sc0 sc1"
               : "=v"(r) : "v"(p) : "memory");
  return r;      // NOT ready until s_waitcnt vmcnt(0)!
}

// ---------------------------------------------------------------------------
// f32 -> bf16 conversion of all 15 input tensors (one launch, 4 elems/thread).
// Also zero-inits the recurrence exchange buffer with SYSTEM-scope stores
// (must be visible at the MALL where recur's exchange ops operate).
// ---------------------------------------------------------------------------
struct ConvArgs {
  const float* src[15];
  unsigned short* dst[15];
  long pre[16];          // prefix sums in 4-element chunks
};

__global__ __launch_bounds__(256) void conv_k(ConvArgs a, long total, ull* gx)
{
  if (blockIdx.x < 512){
    // 131072 ull = 1 MB exchange buffer (both parities) -> tag fields read 0.
    __hip_atomic_store(gx + (size_t)blockIdx.x*256 + threadIdx.x, 0ULL,
                       __ATOMIC_RELAXED, __HIP_MEMORY_SCOPE_SYSTEM);
  }
  long stride = (long)gridDim.x * blockDim.x;
  for (long idx = (long)blockIdx.x * blockDim.x + threadIdx.x; idx < total; idx += stride){
    int t = 0;
    #pragma unroll
    for (int j = 0; j < 14; j++) t += (idx >= a.pre[j + 1]) ? 1 : 0;
    long local = idx - a.pre[t];
    float4 v = ((const float4*)a.src[t])[local];
    s16x4 o;
    o[0] = (short)f2bf(v.x); o[1] = (short)f2bf(v.y);
    o[2] = (short)f2bf(v.z); o[3] = (short)f2bf(v.w);
    ((s16x4*)a.dst[t])[local] = o;
  }
}

// ---------------------------------------------------------------------------
// Generic C[r,c] = act(A @ W^T + bias (+bias2) (+addsrc)),  C is ROWSx512.
// 128x128 tile, BK=64, 4 waves (2x2 of 64x64), mfma_f32_16x16x32_bf16.
// ROUND-0 single-buffer version: measured 814us for the GEMM chain vs 841-850
// with the explicit double-buffer pipeline (m99/m100: explicit dbuf neutral
// or worse -- implicit 2-block/CU overlap already captures it).
// ---------------------------------------------------------------------------
__global__ __launch_bounds__(256, 2) void gemm_k(
    const unsigned short* __restrict__ A, int lda,
    const unsigned short* __restrict__ W, int ldb,
    const unsigned short* __restrict__ bias,
    const unsigned short* __restrict__ bias2,
    const unsigned short* __restrict__ addsrc,
    void* __restrict__ C,
    int K, int act, int out_f32)
{
  __shared__ unsigned short As[128*64];
  __shared__ unsigned short Bs[128*64];
  const int tid = threadIdx.x, w = tid >> 6, l = tid & 63;
  const int wm = w >> 1, wn = w & 1;
  const int lr = l & 15, lk = (l >> 4) * 8;
  const long row0 = (long)blockIdx.x * 128;
  const int  col0 = blockIdx.y * 128;

  f32x4 acc[4][4] = {};

  for (int k0 = 0; k0 < K; k0 += 64){
    __syncthreads();
    #pragma unroll
    for (int i = 0; i < 4; i++){
      int chunk = i*256 + tid;
      int r = chunk >> 3, kc = (chunk & 7) * 8;
      gl_lds16(A + (row0 + r)*lda + k0 + kc, (unsigned short*)As + (i*256 + w*64)*8);
      gl_lds16(W + (long)(col0 + r)*ldb + k0 + kc, (unsigned short*)Bs + (i*256 + w*64)*8);
    }
    asm volatile("s_waitcnt vmcnt(0)" ::: "memory");
    __syncthreads();
    #pragma unroll
    for (int ks = 0; ks < 2; ks++){
      bf16x8 a[4], b[4];
      #pragma unroll
      for (int mt = 0; mt < 4; mt++) a[mt] = *(const bf16x8*)&As[(wm*64 + mt*16 + lr)*64 + ks*32 + lk];
      #pragma unroll
      for (int nt = 0; nt < 4; nt++) b[nt] = *(const bf16x8*)&Bs[(wn*64 + nt*16 + lr)*64 + ks*32 + lk];
      #pragma unroll
      for (int mt = 0; mt < 4; mt++)
        #pragma unroll
        for (int nt = 0; nt < 4; nt++)
          acc[mt][nt] = __builtin_amdgcn_mfma_f32_16x16x32_bf16(a[mt], b[nt], acc[mt][nt], 0, 0, 0);
    }
  }

  #pragma unroll
  for (int nt = 0; nt < 4; nt++){
    int c = col0 + wn*64 + nt*16 + lr;
    float bv = bf2f(bias[c]);
    if (bias2) bv += bf2f(bias2[c]);
    #pragma unroll
    for (int mt = 0; mt < 4; mt++){
      #pragma unroll
      for (int i = 0; i < 4; i++){
        long r = row0 + wm*64 + mt*16 + (l >> 4)*4 + i;
        float v = acc[mt][nt][i] + bv;
        if (addsrc) v += bf2f(addsrc[r*512 + c]);
        if (act) v = fmaxf(v, 0.f);
        if (out_f32) ((float*)C)[r*512 + c] = v;
        else ((unsigned short*)C)[r*512 + c] = f2bf(v);
      }
    }
  }
}

// ---------------------------------------------------------------------------
// Recurrence v17: h_t = tanh(x_ih[:,t,:] + h_{t-1} @ W_hh^T), H[:,t,:] = h_t.
//
// = v10 (round-8 best, 1160us) with ONE change: s_sleep(7) -> s_sleep(13).
// Corrected-units model: FETCH/WRITE are KB, so there was never a probe
// flood; the per-step cost is serial latency: store-visibility ~1100cy +
// probe RT ~900cy. v10's probe issued at +450cy arrived stale -> retry added
// a second RT. Issuing at +832cy makes the first probe land after peers'
// stores are visible: ~832+900 vs ~450+900+900 = ~-500 cyc/step. Pure
// timing change; zero correctness surface (retry loop still tag-gated).
// ---------------------------------------------------------------------------
__global__ __launch_bounds__(256, 1) void recur_k(
    const unsigned short* __restrict__ xih,   // (B,T,512) bf16
    const unsigned short* __restrict__ Whh,   // (512,512) bf16
    unsigned short* __restrict__ H,           // (B,T,512) bf16
    ull* __restrict__ gx)                     // [2 parity][16 g][16 frag][256]
{
  extern __shared__ unsigned short lds[];     // 128 KB
  unsigned short* Wf  = lds;                  // startup: 128 frags x 512 shorts
  unsigned short* hx0 = lds;                  // after overlay: tile0 (16 KB)
  unsigned short* hx1 = lds + 8192;           // tile1 (16 KB)

  const int tid = threadIdx.x, w = tid >> 6, l = tid & 63;
  const int lr = l & 15, hi = l >> 4;
  const int g = blockIdx.x & 15, q = blockIdx.x >> 4;
  const int b0 = g * 16;

  // Stage fragment-ordered weight panel (v6-verified indexing).
  #pragma unroll
  for (int i = 0; i < 32; i++){
    int cid = i*256 + tid;                    // 8192 16B chunks
    int fa = cid >> 6, ln = cid & 63;
    int fw = fa >> 5, fnt = (fa >> 4) & 1, fks = fa & 15;
    int row = q*128 + fw*32 + fnt*16 + (ln & 15);
    int col = fks*32 + (ln >> 4)*8;
    *(bf16x8*)&Wf[cid*8] = *(const bf16x8*)&Whh[row*512 + col];
  }
  __syncthreads();

  // Pull this wave's 32 fragments into registers (AGPR-backed at 1 wave/SIMD;
  // MFMA reads them directly) and pin so they cannot be rematerialized.
  bf16x8 wa0[16], wa1[16];
  #pragma unroll
  for (int ks = 0; ks < 16; ks++){
    wa0[ks] = *(const bf16x8*)(Wf + (w*32 +      ks)*512 + l*8);
    wa1[ks] = *(const bf16x8*)(Wf + (w*32 + 16 + ks)*512 + l*8);
  }
  #pragma unroll
  for (int ks = 0; ks < 16; ks++){
    asm volatile("" : "+v"(wa0[ks]));
    asm volatile("" : "+v"(wa1[ks]));
  }
  __syncthreads();   // all reg-reads done -> weight LDS region is dead

  // Overlay: zero both h tiles (h_0 = 0).
  {
    ull* z = (ull*)lds;
    #pragma unroll
    for (int i = 0; i < 16; i++) z[i*256 + tid] = 0;   // 4096 ull = 32 KB
  }
  __syncthreads();

  const unsigned short* hrd0 = hx0 + l*8;               // + ks*512
  const unsigned short* hrd1 = hx1 + l*8;
  unsigned short*       hwr0 = hx0 + (w*4)*512 + l*8;   // + j*512
  unsigned short*       hwr1 = hx1 + (w*4)*512 + l*8;

  const int colq = q*128 + w*32;
  const long xb = ((long)(b0 + lr) * RT) * 512 + colq + hi*4;
  const unsigned short* xr = xih + xb;        // +16 for nt=1; advances 512/step
  unsigned short*       hr = H   + xb;

  const int fq = q*4 + w;                     // this wave's fragment id
  // Producer slot bases (ull index; e0/e2 are even -> 16B aligned).
  const int e0 = (((hi >> 1)    )*16 + lr)*4 + (hi & 1)*2;   // nt=0, i=0,1
  const int e2 = ((2 + (hi >> 1))*16 + lr)*4 + (hi & 1)*2;   // nt=1, i=0,1

  uint2 xu0 = *(const uint2*)(xr);
  uint2 xu1 = *(const uint2*)(xr + 16);

  for (int t = 0; t < RT; t++){
    // ---- MFMA: weights from registers, h_{t-1} from LDS tile[t&1] ----
    const unsigned short* hfb = (t & 1) ? hrd1 : hrd0;
    f32x4 acc0 = {}, acc1 = {};
    #pragma unroll
    for (int ks = 0; ks < 16; ks++){
      bf16x8 hf = *(const bf16x8*)(hfb + ks*512);
      acc0 = __builtin_amdgcn_mfma_f32_16x16x32_bf16(wa0[ks], hf, acc0, 0, 0, 0);
      acc1 = __builtin_amdgcn_mfma_f32_16x16x32_bf16(wa1[ks], hf, acc1, 0, 0, 0);
    }

    // ---- h = tanh(acc + x_ih), pack (RNE, bit-identical) ----
    uint2 P0, P1;
    {
      float v0 = tanh_fast(acc0[0] + blo(xu0.x));
      float v1 = tanh_fast(acc0[1] + bhi(xu0.x));
      float v2 = tanh_fast(acc0[2] + blo(xu0.y));
      float v3 = tanh_fast(acc0[3] + bhi(xu0.y));
      P0.x = cvt_pk_bf16(v0, v1); P0.y = cvt_pk_bf16(v2, v3);
      float u0 = tanh_fast(acc1[0] + blo(xu1.x));
      float u1 = tanh_fast(acc1[1] + bhi(xu1.x));
      float u2 = tanh_fast(acc1[2] + blo(xu1.y));
      float u3 = tanh_fast(acc1[3] + bhi(xu1.y));
      P1.x = cvt_pk_bf16(u0, u1); P1.y = cvt_pk_bf16(u2, u3);
    }

    // ---- fire-and-forget: 2x16B tagged exchange stores + H row ----
    const unsigned tg   = (unsigned)(t + 1);
    const unsigned tghi = tg << 16;
    {
      ull* gs = gx + ((size_t)((t & 1)*16 + g))*4096 + (size_t)fq*256;
      i32x4 D0, D1;
      D0[0] = (int)(tghi | (P0.x & 0xffffu)); D0[1] = (int)(tghi | (P0.x >> 16));
      D0[2] = (int)(tghi | (P0.y & 0xffffu)); D0[3] = (int)(tghi | (P0.y >> 16));
      D1[0] = (int)(tghi | (P1.x & 0xffffu)); D1[1] = (int)(tghi | (P1.x >> 16));
      D1[2] = (int)(tghi | (P1.y & 0xffffu)); D1[3] = (int)(tghi | (P1.y >> 16));
      st16_mall(gs + e0, D0);
      st16_mall(gs + e2, D1);
      *(uint2*)(hr)      = P0;
      *(uint2*)(hr + 16) = P1;
      hr += 512;
    }

    // Prefetch next x_ih (flies during the sleep).
    if (t + 1 < RT){
      xu0 = *(const uint2*)(xr + 512);
      xu1 = *(const uint2*)(xr + 528);
    }
    xr += 512;

    if (t + 1 < RT){
      __builtin_amdgcn_s_sleep(13);  // ~832 cyc: past peers' store-visibility
      const ull* pb = gx + ((size_t)((t & 1)*16 + g))*4096 + (size_t)(w*4)*256 + l*4;
      i32x4 da[8];
      #pragma unroll
      for (int j = 0; j < 4; j++){
        da[2*j]   = ld16_mall(pb + j*256);
        da[2*j+1] = ld16_mall(pb + j*256 + 2);
      }
      for (;;){
        asm volatile("s_waitcnt vmcnt(0)" ::: "memory");
        __builtin_amdgcn_sched_barrier(0);
        unsigned bad = 0;
        #pragma unroll
        for (int j = 0; j < 8; j++){
          bad |= ((unsigned)da[j][0] >> 16) ^ tg;
          bad |= ((unsigned)da[j][1] >> 16) ^ tg;
          bad |= ((unsigned)da[j][2] >> 16) ^ tg;
          bad |= ((unsigned)da[j][3] >> 16) ^ tg;
        }
        if (__all(bad == 0)) break;
        #pragma unroll
        for (int j = 0; j < 4; j++){
          da[2*j]   = ld16_mall(pb + j*256);
          da[2*j+1] = ld16_mall(pb + j*256 + 2);
        }
      }
      // ---- strip tags, write clean fragments into tile[(t+1)&1] ----
      unsigned short* hw = (t & 1) ? hwr0 : hwr1;
      #pragma unroll
      for (int j = 0; j < 4; j++){
        i32x4 a = da[2*j], b = da[2*j+1];
        i32x4 qv;
        qv[0] = (a[0] & 0xffff) | (a[1] << 16);
        qv[1] = (a[2] & 0xffff) | (a[3] << 16);
        qv[2] = (b[0] & 0xffff) | (b[1] << 16);
        qv[3] = (b[2] & 0xffff) | (b[3] << 16);
        *(i32x4*)(hw + j*512) = qv;
      }
    }
    // LDS-only barrier: no vmcnt(0) store-drain.
    asm volatile("s_waitcnt lgkmcnt(0)" ::: "memory");
    __builtin_amdgcn_s_barrier();
    asm volatile("" ::: "memory");
  }
}

// ---------------------------------------------------------------------------
// Fused blend: gate = sigmoid([x|h]@W_g^T + b_g); x_proj = x@W_ip^T + b_ip;
// h_proj = h@W_hp^T + b_hp; out = gate*h_proj + (1-gate)*x_proj.
// Two-phase K=768 (phase1: x/K=256 with acc_p=x_proj snapshot; phase2: h/K=512).
// ---------------------------------------------------------------------------
__global__ __launch_bounds__(256, 2) void blend_k(
    const unsigned short* __restrict__ X,    // (ROWS,256) bf16
    const unsigned short* __restrict__ Hm,   // (ROWS,512) bf16
    const unsigned short* __restrict__ Wg,   // (512,768) bf16
    const unsigned short* __restrict__ Wip,  // (512,256) bf16
    const unsigned short* __restrict__ Whp,  // (512,512) bf16
    const unsigned short* __restrict__ bg,
    const unsigned short* __restrict__ bip,
    const unsigned short* __restrict__ bhp,
    unsigned short* __restrict__ Out)
{
  __shared__ unsigned short As[128*64];
  __shared__ unsigned short Gs[128*64];
  __shared__ unsigned short Ps[128*64];
  const int tid = threadIdx.x, w = tid >> 6, l = tid & 63;
  const int wm = w >> 1, wn = w & 1;
  const int lr = l & 15, lk = (l >> 4) * 8;
  const long row0 = (long)blockIdx.x * 128;
  const int  col0 = blockIdx.y * 128;

  f32x4 accg[4][4] = {}, accp[4][4] = {};
  unsigned int xpp[4][4][2];

  #pragma unroll 1
  for (int k0 = 0; k0 < 768; k0 += 64){
    const bool ph1 = (k0 < 256);
    __syncthreads();
    #pragma unroll
    for (int i = 0; i < 4; i++){
      int chunk = i*256 + tid;
      int r = chunk >> 3, kc = (chunk & 7) * 8;
      const unsigned short* asrc = ph1 ? (X  + (row0 + r)*256 + k0 + kc)
                                       : (Hm + (row0 + r)*512 + (k0 - 256) + kc);
      gl_lds16(asrc, (unsigned short*)As + (i*256 + w*64)*8);
      gl_lds16(Wg + (long)(col0 + r)*768 + k0 + kc, (unsigned short*)Gs + (i*256 + w*64)*8);
      const unsigned short* psrc = ph1 ? (Wip + (col0 + r)*256 + k0 + kc)
                                       : (Whp + (col0 + r)*512 + (k0 - 256) + kc);
      gl_lds16(psrc, (unsigned short*)Ps + (i*256 + w*64)*8);
    }
    asm volatile("s_waitcnt vmcnt(0)" ::: "memory");
    __syncthreads();
    #pragma unroll
    for (int ks = 0; ks < 2; ks++){
      bf16x8 a[4], gq[4], pq[4];
      #pragma unroll
      for (int mt = 0; mt < 4; mt++) a[mt]  = *(const bf16x8*)&As[(wm*64 + mt*16 + lr)*64 + ks*32 + lk];
      #pragma unroll
      for (int nt = 0; nt < 4; nt++){
        gq[nt] = *(const bf16x8*)&Gs[(wn*64 + nt*16 + lr)*64 + ks*32 + lk];
        pq[nt] = *(const bf16x8*)&Ps[(wn*64 + nt*16 + lr)*64 + ks*32 + lk];
      }
      #pragma unroll
      for (int mt = 0; mt < 4; mt++)
        #pragma unroll
        for (int nt = 0; nt < 4; nt++){
          accg[mt][nt] = __builtin_amdgcn_mfma_f32_16x16x32_bf16(a[mt], gq[nt], accg[mt][nt], 0, 0, 0);
          accp[mt][nt] = __builtin_amdgcn_mfma_f32_16x16x32_bf16(a[mt], pq[nt], accp[mt][nt], 0, 0, 0);
        }
    }
    if (k0 == 192){   // end of phase 1: snapshot x_proj, reset acc_p for h_proj
      #pragma unroll
      for (int mt = 0; mt < 4; mt++)
        #pragma unroll
        for (int nt = 0; nt < 4; nt++){
          xpp[mt][nt][0] = (unsigned)f2bf(accp[mt][nt][0]) | ((unsigned)f2bf(accp[mt][nt][1]) << 16);
          xpp[mt][nt][1] = (unsigned)f2bf(accp[mt][nt][2]) | ((unsigned)f2bf(accp[mt][nt][3]) << 16);
          accp[mt][nt] = (f32x4){0.f, 0.f, 0.f, 0.f};
        }
    }
  }

  #pragma unroll
  for (int nt = 0; nt < 4; nt++){
    int c = col0 + wn*64 + nt*16 + lr;
    float bgv = bf2f(bg[c]), bipv = bf2f(bip[c]), bhpv = bf2f(bhp[c]);
    #pragma unroll
    for (int mt = 0; mt < 4; mt++){
      #pragma unroll
      for (int i = 0; i < 4; i++){
        long r = row0 + wm*64 + mt*16 + (l >> 4)*4 + i;
        float g  = sigmoid_fast(accg[mt][nt][i] + bgv);
        float hp = accp[mt][nt][i] + bhpv;
        unsigned u = xpp[mt][nt][i >> 1];
        float xp = bf2f((unsigned short)((i & 1) ? (u >> 16) : (u & 0xffff))) + bipv;
        float v = g * hp + (1.f - g) * xp;
        Out[r*512 + c] = f2bf(v);
      }
    }
  }
}

// ---------------------------------------------------------------------------
// Buffer plan. d_out (268 MB, f32 final) doubles as bf16 scratch; W_o/b_o
// live in d_ws so K5 never reads what it writes:
//   d_out [0, 64Mi):             x_bf16 (67.1 MB)
//   d_out [64Mi, +2.9MB):        converted weights W_ih..b_r
//   d_out [72Mi, +134MB):        x_ih, later blended (bf16)  [ends 209,715,200)
//   d_out [209,715,200, +1MB):   gx tagged exchange buffer (zeroed by conv_k)
//   d_ws  [0, 134MB):            H, later u (bf16)
//   d_ws  [134MB, +525KB):       W_o, b_o (bf16)
// conv -> K1(x_ih) -> K2(H) -> K3(blended) -> K4(u) -> K5(f32 out).
// Every stage's read set is disjoint from its write set; gx is dead before
// K5 overwrites d_out.
// ---------------------------------------------------------------------------
extern "C" void kernel_launch(void* const* d_in, const int* in_sizes, int n_in,
                              void* d_out, int out_size, void* d_ws, size_t ws_size,
                              hipStream_t stream)
{
  static const long nelem[15] = {
    (long)ROWS*256,        // x
    512*256, 512,          // W_ih, b_ih
    512*512, 512,          // W_hh, b_hh
    512*256, 512,          // W_ip, b_ip
    512*512, 512,          // W_hp, b_hp
    512*768, 512,          // W_g,  b_g
    512*512, 512,          // W_r,  b_r
    512*512, 512           // W_o,  b_o
  };

  unsigned char* ob = (unsigned char*)d_out;
  unsigned char* wb = (unsigned char*)d_ws;
  ConvArgs ca;
  long pre = 0;
  size_t doff = 0;
  for (int i = 0; i < 15; i++){
    ca.src[i] = (const float*)d_in[i];
    if (i == 13)      ca.dst[i] = (unsigned short*)(wb + 134217728u);   // W_o
    else if (i == 14) ca.dst[i] = (unsigned short*)(wb + 134742016u);   // b_o
    else              ca.dst[i] = (unsigned short*)(ob + doff);
    ca.pre[i] = pre;
    pre += nelem[i] / 4;
    if (i == 0) doff = 67108864u;
    else if (i < 13) doff += (size_t)nelem[i] * 2;
  }
  ca.pre[15] = pre;
  const long total_chunks = pre;   // 8,815,488

  const unsigned short* xb  = ca.dst[0];
  const unsigned short* Wih = ca.dst[1];
  const unsigned short* bih = ca.dst[2];
  const unsigned short* Whh = ca.dst[3];
  const unsigned short* bhh = ca.dst[4];
  const unsigned short* Wip = ca.dst[5];
  const unsigned short* bip = ca.dst[6];
  const unsigned short* Whp = ca.dst[7];
  const unsigned short* bhp = ca.dst[8];
  const unsigned short* Wg  = ca.dst[9];
  const unsigned short* bg  = ca.dst[10];
  const unsigned short* Wr  = ca.dst[11];
  const unsigned short* br  = ca.dst[12];
  const unsigned short* Wo  = ca.dst[13];
  const unsigned short* bo  = ca.dst[14];

  unsigned short* xih  = (unsigned short*)(ob + 75497472u);    // 72 MiB offset
  ull*            gxb  = (ull*)(ob + 209715200u);              // 1 MB exchange
  unsigned short* wsb  = (unsigned short*)d_ws;                // H, later u

  dim3 grid(ROWS / 128, 4), block(256);

  // K0: convert all f32 inputs to bf16 + zero the tagged exchange buffer.
  conv_k<<<2048, 256, 0, stream>>>(ca, total_chunks, gxb);

  // K1: x_ih = x @ W_ih^T + b_ih + b_hh  -> xih (bf16)
  gemm_k<<<grid, block, 0, stream>>>(xb, 256, Wih, 256, bih, bhh, nullptr, xih, 256, 0, 0);

  // K2: recurrence -> H in ws (64 blocks x 256 threads, 131,072 B dyn LDS)
  static const int kRecurLds = 128 * 1024;
  (void)hipFuncSetAttribute((const void*)recur_k, hipFuncAttributeMaxDynamicSharedMemorySize, kRecurLds);
  recur_k<<<64, 256, kRecurLds, stream>>>(xih, Whh, wsb, gxb);

  // K3: blended (fused gate/x_proj/h_proj) -> xih region (x_ih dead)
  blend_k<<<grid, block, 0, stream>>>(xb, wsb, Wg, Wip, Whp, bg, bip, bhp, xih);

  // K4: u = relu(blended @ W_r^T + b_r + blended) -> ws (H dead)
  gemm_k<<<grid, block, 0, stream>>>(xih, 512, Wr, 512, br, nullptr, xih, wsb, 512, 1, 0);

  // K5: out = u @ W_o^T + b_o -> d_out (f32; reads only from d_ws)
  gemm_k<<<grid, block, 0, stream>>>(wsb, 512, Wo, 512, bo, nullptr, nullptr, d_out, 512, 0, 1);
}